// Round 1
// baseline (11279.815 us; speedup 1.0000x reference)
//
#include <hip/hip_runtime.h>
#include <cstddef>
#include <cstdint>
#include <math.h>

// B=64, T=512, V=50002, E=300, H=256, K=11, START=9, STOP=10
// Output: [64 score][64*512 path] floats = 32832.

__device__ __forceinline__ float sigmf_(float x){ return 1.0f/(1.0f+expf(-x)); }

// ---------------- generic zero ----------------
__global__ void k_zero(float* __restrict__ p, int n){
  for (int i = blockIdx.x*blockDim.x + threadIdx.x; i < n; i += gridDim.x*blockDim.x) p[i] = 0.f;
}

// ---------------- gather embeddings slab: X[C*T,304] zero-padded ----------------
__global__ void k_gather(const int* __restrict__ sent, const float* __restrict__ emb,
                         float4* __restrict__ X, int b0, int t0, int logT, int Tm1, int total){
  int idx = blockIdx.x*256 + threadIdx.x;
  if (idx >= total) return;
  int m = idx / 76, k4 = idx - m*76;
  int bl = m >> logT, t = m & Tm1;
  float4 v = make_float4(0.f,0.f,0.f,0.f);
  if (k4 < 75) v = ((const float4*)emb)[(size_t)sent[(size_t)(b0+bl)*512 + t0 + t]*75 + k4];
  X[idx] = v;
}

// ---------------- transpose w_ih into wT [dinPad,1024] (R5-proven) ----------------
__global__ void k_prepw(const float* __restrict__ w, float* __restrict__ wT, int din, int dinPad){
  int total = dinPad*1024;
  for (int idx = blockIdx.x*blockDim.x + threadIdx.x; idx < total; idx += gridDim.x*blockDim.x){
    int k = idx >> 10, n = idx & 1023;
    wT[idx] = (k < din) ? w[n*din + k] : 0.f;
  }
}

// ------- dual fp32 GEMM (z=0/1): C[M,1024] = A[M(strided rows),lda] @ Bm[K,1024] + bias -------
// (byte-identical to R5's proven k_gemm2)
__global__ __launch_bounds__(256) void k_gemm2(
    const float* __restrict__ A0, const float* __restrict__ A1, int lda, int kTiles,
    int aBstride, int sOff0, int sOff1, int logT, int Tm1,
    const float* __restrict__ B0, const float* __restrict__ B1,
    const float* __restrict__ bias0, const float* __restrict__ bias1,
    float* __restrict__ C0, float* __restrict__ C1){
  __shared__ float As[16][132];
  __shared__ float Bs[16][132];
  const int z = blockIdx.z;
  const float* A   = z ? A1 : A0;
  const float* Bm  = z ? B1 : B0;
  const float* bias= z ? bias1 : bias0;
  float* Cc        = z ? C1 : C0;
  const int sOff   = z ? sOff1 : sOff0;
  const int t  = threadIdx.x;
  const int tx = t & 15, ty = t >> 4;
  const int m0 = blockIdx.y * 128, n0 = blockIdx.x * 128;
  const int arow = t >> 2, ak = (t & 3) * 4;
  const int brow = t >> 5, bc = (t & 31) * 4;
  const int gm0 = m0 + arow, gm1 = m0 + arow + 64;
  const size_t r0 = (size_t)(gm0 >> logT)*aBstride + sOff + (gm0 & Tm1);
  const size_t r1 = (size_t)(gm1 >> logT)*aBstride + sOff + (gm1 & Tm1);
  float acc[8][8] = {};
  for (int kt = 0; kt < kTiles; ++kt){
    const int kb = kt * 16;
    float4 a0 = *(const float4*)(A + r0*lda + kb + ak);
    float4 a1 = *(const float4*)(A + r1*lda + kb + ak);
    float4 b0 = *(const float4*)(Bm + (size_t)(kb+brow)*1024 + n0 + bc);
    float4 b1 = *(const float4*)(Bm + (size_t)(kb+brow+8)*1024 + n0 + bc);
    __syncthreads();
    As[ak+0][arow] = a0.x; As[ak+1][arow] = a0.y; As[ak+2][arow] = a0.z; As[ak+3][arow] = a0.w;
    As[ak+0][arow+64] = a1.x; As[ak+1][arow+64] = a1.y; As[ak+2][arow+64] = a1.z; As[ak+3][arow+64] = a1.w;
    *(float4*)&Bs[brow  ][bc] = b0;
    *(float4*)&Bs[brow+8][bc] = b1;
    __syncthreads();
    #pragma unroll
    for (int k = 0; k < 16; ++k){
      float av[8], bv[8];
      *(float4*)&av[0] = *(const float4*)&As[k][ty*8];
      *(float4*)&av[4] = *(const float4*)&As[k][ty*8+4];
      *(float4*)&bv[0] = *(const float4*)&Bs[k][tx*8];
      *(float4*)&bv[4] = *(const float4*)&Bs[k][tx*8+4];
      #pragma unroll
      for (int i = 0; i < 8; ++i)
        #pragma unroll
        for (int jj = 0; jj < 8; ++jj)
          acc[i][jj] = fmaf(av[i], bv[jj], acc[i][jj]);
    }
  }
  float bvals[8];
  *(float4*)&bvals[0] = *(const float4*)(bias + n0 + tx*8);
  *(float4*)&bvals[4] = *(const float4*)(bias + n0 + tx*8 + 4);
  float* Cp = Cc + (size_t)(m0 + ty*8)*1024 + n0 + tx*8;
  #pragma unroll
  for (int i = 0; i < 8; ++i){
    float4 o0 = make_float4(acc[i][0]+bvals[0], acc[i][1]+bvals[1], acc[i][2]+bvals[2], acc[i][3]+bvals[3]);
    float4 o1 = make_float4(acc[i][4]+bvals[4], acc[i][5]+bvals[5], acc[i][6]+bvals[6], acc[i][7]+bvals[7]);
    *(float4*)(Cp + (size_t)i*1024)     = o0;
    *(float4*)(Cp + (size_t)i*1024 + 4) = o1;
  }
}

// ---------------- LSTM recurrence: R5/R6 math, R7 sync restructure ----------------
// DELTA vs prev round (math/FMA order byte-identical -> bitwise-same results):
//  1) XCD co-location: partner blocks (same chain, other hh) are blk^8 ->
//     same XCD under round-robin dispatch. Perf heuristic only.
//  2) flags padded to 64B/flag (no false sharing of partner flags).
//  3) parallel spin: all t<128 spin RELAXED + one acquire fence, then load
//     partner h directly (removes spin->barrier->load serialization; 4->3
//     barriers per step).
//  4) hob (output h) store moved after flag release, into the spin shadow;
//     B2 now drains only the 512B hxme exchange store.
__global__ __launch_bounds__(512, 2) void k_lstm2s(
    const float* __restrict__ xwF, const float* __restrict__ xwB,
    const float* __restrict__ whhf, const float* __restrict__ whhb,
    float* __restrict__ hout, int hBstride, int tOffF, int tOffB,
    int T, int epoch,
    float* __restrict__ hx, int* __restrict__ flags,
    float* __restrict__ hsave, float* __restrict__ csave)
{
  __shared__ float hfull[256];
  __shared__ float gls[512];
  __shared__ float wtail[512*66];       // 135 KB: per-thread 64-float W tail (q=24..31)
  const int blk = blockIdx.x;
  const int hh = (blk >> 3) & 1;                    // partner = blk ^ 8 (same XCD mod 8)
  const int chain = (blk & 7) | ((blk >> 4) << 3);  // bijection over [0, NB/2)
  const int b_local = chain >> 1;
  const int dir = chain & 1;
  const int t = threadIdx.x;
  const int wv = t >> 6, lane = t & 63;
  const int kap = lane >> 5, li = lane & 31;
  const int r0 = wv*64 + li*2;          // block-local rows r0, r0+1
  const int rK = r0 + kap;              // row this thread finalizes
  const int gateK = rK >> 7;
  float4 w0[24], w1[24];
  {
    const float* whh = dir ? whhb : whhf;
    const int g0 = r0 >> 7, i0 = r0 & 127;
    const float* a = whh + (size_t)(g0*256 + hh*128 + i0)*256 + kap*128;
    const float* b = a + 256;           // rowB = rowA + 1
    #pragma unroll
    for (int q = 0; q < 24; ++q){ w0[q] = *(const float4*)(a + q*4); w1[q] = *(const float4*)(b + q*4); }
    for (int q = 24; q < 32; ++q){
      #pragma unroll
      for (int e = 0; e < 4; ++e){
        wtail[t*66 + (q-24)*4 + e]      = a[q*4 + e];
        wtail[t*66 + 32 + (q-24)*4 + e] = b[q*4 + e];
      }
    }
  }
  if (t < 256) hfull[t] = hsave[chain*256 + t];
  float c = (t < 128) ? csave[chain*256 + hh*128 + t] : 0.f;
  __syncthreads();
  const int xcol = gateK*256 + hh*128 + (rK & 127);
  const float* xb = (dir ? xwB : xwF) + (size_t)b_local*T*1024 + xcol;
  float* hxme        = hx + (size_t)(chain*2 + hh)*256;        // [parity][128]
  const float* hxpt  = hx + (size_t)(chain*2 + (1-hh))*256;
  int* flg  = flags + (chain*2 + hh)*16;        // 64B-padded flags
  int* flgp = flags + (chain*2 + (1-hh))*16;
  const int tOff = dir ? tOffB : tOffF;
  float* hob = hout + (size_t)b_local*hBstride + dir*256 + hh*128;
  const float* wtb = &wtail[t*66];
  float xg = xb[(size_t)(dir ? (T-1) : 0)*1024];
  for (int s = 0; s < T; ++s){
    const int tt = dir ? (T-1-s) : s;
    float xn = 0.f;
    if (s < T-1) xn = xb[(size_t)(dir ? (T-2-s) : (s+1))*1024];   // prefetch
    float p0 = 0.f, p1 = 0.f;
    const float4* h4 = ((const float4*)hfull) + kap*32;
    #pragma unroll
    for (int q = 0; q < 24; ++q){
      float4 hv = h4[q];                        // wave-uniform addr -> LDS broadcast
      p0 = fmaf(w0[q].x, hv.x, p0);  p1 = fmaf(w1[q].x, hv.x, p1);
      p0 = fmaf(w0[q].y, hv.y, p0);  p1 = fmaf(w1[q].y, hv.y, p1);
      p0 = fmaf(w0[q].z, hv.z, p0);  p1 = fmaf(w1[q].z, hv.z, p1);
      p0 = fmaf(w0[q].w, hv.w, p0);  p1 = fmaf(w1[q].w, hv.w, p1);
    }
    #pragma unroll
    for (int q = 24; q < 32; ++q){              // LDS tail, same FMA order
      float4 hv = h4[q];
      const int o = (q-24)*4;
      p0 = fmaf(wtb[o+0], hv.x, p0);  p1 = fmaf(wtb[32+o+0], hv.x, p1);
      p0 = fmaf(wtb[o+1], hv.y, p0);  p1 = fmaf(wtb[32+o+1], hv.y, p1);
      p0 = fmaf(wtb[o+2], hv.z, p0);  p1 = fmaf(wtb[32+o+2], hv.z, p1);
      p0 = fmaf(wtb[o+3], hv.w, p0);  p1 = fmaf(wtb[32+o+3], hv.w, p1);
    }
    float q0 = p0 + __shfl_xor(p0, 32, 64);     // combine k-halves
    float q1 = p1 + __shfl_xor(p1, 32, 64);
    float acc = (kap ? q1 : q0) + xg;
    float act = (gateK == 2) ? tanhf(acc) : sigmf_(acc);   // i,f,o sigmoid; g tanh
    gls[rK] = act;
    __syncthreads();                            // B1: gates ready
    float hval = 0.f;
    if (t < 128){
      c = gls[128 + t]*c + gls[t]*gls[256 + t];
      hval = gls[384 + t]*tanhf(c);
      hfull[hh*128 + t] = hval;
      hxme[(s & 1)*128 + t] = hval;             // publish data (parity dbuf)
    }
    __syncthreads();                            // B2: exchange stores drained
    if (t == 0)
      __hip_atomic_store(flg, epoch + s + 1, __ATOMIC_RELEASE, __HIP_MEMORY_SCOPE_AGENT);
    if (t < 128){
      hob[(size_t)(tOff + tt)*512 + t] = hval;  // off critical path (spin shadow)
      int lim = 0;                              // bounded spin (hang fuse)
      while (__hip_atomic_load(flgp, __ATOMIC_RELAXED, __HIP_MEMORY_SCOPE_AGENT) < epoch + s + 1
             && ++lim < (1<<20)) {}
      __builtin_amdgcn_fence(__ATOMIC_ACQUIRE, "agent");
      hfull[(1 - hh)*128 + t] = hxpt[(s & 1)*128 + t];
    }
    __syncthreads();                            // B3: hfull ready for next step
    xg = xn;
  }
  if (t < 128){
    hsave[chain*256 + hh*128 + t] = hfull[hh*128 + t];
    csave[chain*256 + hh*128 + t] = c;
  }
}

// ---------------- feats accumulation (one dir half per call; R5-proven) ----------------
__global__ __launch_bounds__(256) void k_feats_half(
    const float* __restrict__ h1s, const float* __restrict__ fcw, const float* __restrict__ fcb,
    float* __restrict__ feats, int b0, int logT, int Tm1, int tG0, int dir){
  int wv = threadIdx.x >> 6, lane = threadIdx.x & 63;
  int m = blockIdx.x*4 + wv;                 // m = bl*T + tl
  const float4* row = (const float4*)(h1s + (size_t)m*512 + dir*256);
  float4 rv = row[lane];
  int bl = m >> logT, tl = m & Tm1;
  size_t fbase = ((size_t)(b0 + bl)*512 + tG0 + tl)*11;
  #pragma unroll
  for (int n = 0; n < 11; ++n){
    const float4* wr = (const float4*)(fcw + n*512 + dir*256);
    float4 w4 = wr[lane];
    float p = rv.x*w4.x + rv.y*w4.y + rv.z*w4.z + rv.w*w4.w;
    #pragma unroll
    for (int off = 32; off > 0; off >>= 1) p += __shfl_down(p, off, 64);
    if (lane == 0){
      float add = (dir == 0) ? (p + fcb[n]) : p;
      feats[fbase + n] += add;
    }
  }
}

// ---------------- Viterbi: 1 wave per batch (R2/R5-proven) ----------------
__global__ __launch_bounds__(256) void k_viterbi(const float* __restrict__ feats,
                        const float* __restrict__ trans, float* __restrict__ out){
  __shared__ unsigned char bp[4][512][12];
  const int wave = threadIdx.x >> 6, lane = threadIdx.x & 63;
  const int b = blockIdx.x*4 + wave;
  const int j = lane;
  float tr[11];
  float fv;
  if (j < 11){
    #pragma unroll
    for (int p = 0; p < 11; ++p) tr[p] = trans[j*11 + p];
    fv = (j == 9) ? 0.f : -1000.f;
  } else {
    #pragma unroll
    for (int p = 0; p < 11; ++p) tr[p] = -1e30f;
    fv = -1e30f;
  }
  for (int t = 0; t < 512; ++t){
    float best = -1e38f; int bestp = 0;
    #pragma unroll
    for (int p = 0; p < 11; ++p){
      float v = __shfl(fv, p, 64) + tr[p];
      if (v > best){ best = v; bestp = p; }   // strict > keeps FIRST max (np.argmax)
    }
    float feat = (j < 11) ? feats[((size_t)b*512 + t)*11 + j] : 0.f;
    fv = best + feat;
    if (j < 11) bp[wave][t][j] = (unsigned char)bestp;
  }
  float term = (j < 11) ? fv + trans[10*11 + j] : -1e38f;
  float best = -1e38f; int bestp = 0;
  #pragma unroll
  for (int p = 0; p < 11; ++p){
    float v = __shfl(term, p, 64);
    if (v > best){ best = v; bestp = p; }
  }
  if (lane == 0){
    out[b] = best;
    float* path = out + 64 + (size_t)b*512;
    int cur = bestp;
    path[511] = (float)cur;
    for (int t = 511; t >= 1; --t){
      cur = bp[wave][t][cur];
      path[t-1] = (float)cur;
    }
  }
}

extern "C" void kernel_launch(void* const* d_in, const int* in_sizes, int n_in,
                              void* d_out, int out_size, void* d_ws, size_t ws_size,
                              hipStream_t stream){
  const int*   sent  = (const int*)d_in[0];
  const float* emb   = (const float*)d_in[2];
  const float* fcw   = (const float*)d_in[3];
  const float* fcb   = (const float*)d_in[4];
  const float* trans = (const float*)d_in[5];
  const float* wih0f = (const float*)d_in[6];
  const float* whh0f = (const float*)d_in[7];
  const float* b0f   = (const float*)d_in[8];
  const float* wih0b = (const float*)d_in[9];
  const float* whh0b = (const float*)d_in[10];
  const float* b0b   = (const float*)d_in[11];
  const float* wih1f = (const float*)d_in[12];
  const float* whh1f = (const float*)d_in[13];
  const float* b1f   = (const float*)d_in[14];
  const float* wih1b = (const float*)d_in[15];
  const float* whh1b = (const float*)d_in[16];
  const float* b1b   = (const float*)d_in[17];

  float* ws = (float*)d_ws;
  // -------- fixed region (flags grown to 64B-padded: 4096 ints) --------
  const size_t o_wT0f = 0;                         // 304*1024
  const size_t o_wT0b = o_wT0f + 311296;
  const size_t o_wT1f = o_wT0b + 311296;           // 512*1024
  const size_t o_wT1b = o_wT1f + 524288;
  const size_t o_hx   = o_wT1b + 524288;           // fp32 planes: 64*2 chains*2 hh*2 par*128 = 65536
  const size_t o_flag = o_hx   + 65536;            // 4096 ints (128 chains * 2 hh * 16-int pad)
  const size_t o_hs   = o_flag + 4096;             // hsave 128 chains * 256 = 32768
  const size_t o_cs   = o_hs   + 32768;            // csave 32768
  const size_t o_feat = o_cs   + 32768;            // 32768*11 = 360448
  const size_t o_var  = o_feat + 360448;           // fixed floats (~8.67 MB)
  float* wT0f = ws + o_wT0f;
  float* wT0b = ws + o_wT0b;
  float* wT1f = ws + o_wT1f;
  float* wT1b = ws + o_wT1b;
  float* hx    = ws + o_hx;
  int*   flags = (int*)(ws + o_flag);
  float* hsave = ws + o_hs;
  float* csave = ws + o_cs;
  float* feats = ws + o_feat;

  // -------- adaptive (C batches, T timesteps) slab sizing (R5 table + (8,64)) --------
  int C = 8, T = 32, logT = 5;
  {
    const int cc[8]  = {64, 64, 32, 32, 16, 16, 8, 8};
    const int tt[8]  = {32, 16, 32, 16, 32, 16, 64, 32};
    const int lt[8]  = { 5,  4,  5,  4,  5,  4,  6,  5};
    for (int i = 0; i < 8; ++i){
      size_t need = (o_var + (size_t)cc[i]*tt[i]*2656 + (size_t)cc[i]*262144)*4;
      if (need <= ws_size){ C = cc[i]; T = tt[i]; logT = lt[i]; break; }
    }
  }
  const int Tm1 = T - 1, S = 512 / T;
  float* XF  = ws + o_var;                        // [C*T,304]  (layer0)
  float* XB  = XF + (size_t)C*T*304;
  float* xwF = XB + (size_t)C*T*304;              // [C*T,1024]
  float* xwB = xwF + (size_t)C*T*1024;
  float* h0  = xwB + (size_t)C*T*1024;            // [C,512,512] fp32
  float* h1s = XF;                                // alias: [C,T,512] (layer1 slab)

  hipLaunchKernelGGL(k_prepw, dim3(512), dim3(256), 0, stream, wih0f, wT0f, 300, 304);
  hipLaunchKernelGGL(k_prepw, dim3(512), dim3(256), 0, stream, wih0b, wT0b, 300, 304);
  hipLaunchKernelGGL(k_prepw, dim3(512), dim3(256), 0, stream, wih1f, wT1f, 512, 512);
  hipLaunchKernelGGL(k_prepw, dim3(512), dim3(256), 0, stream, wih1b, wT1b, 512, 512);
  hipLaunchKernelGGL(k_zero,  dim3(512), dim3(256), 0, stream, feats, 360448);

  for (int b0 = 0; b0 < 64; b0 += C){
    for (int layer = 0; layer < 2; ++layer){
      // zero hx + flags + hsave + csave (contiguous region)
      hipLaunchKernelGGL(k_zero, dim3(256), dim3(256), 0, stream, ws + o_hx, 65536 + 4096 + 65536);
      const float* whF = layer ? whh1f : whh0f;
      const float* whB = layer ? whh1b : whh0b;
      for (int sl = 0; sl < S; ++sl){
        const int sF = sl, sB = S - 1 - sl;
        const int M = C*T;
        if (layer == 0){
          int total = C*T*76;
          hipLaunchKernelGGL(k_gather, dim3((total+255)/256), dim3(256), 0, stream,
                             sent, emb, (float4*)XF, b0, sF*T, logT, Tm1, total);
          hipLaunchKernelGGL(k_gather, dim3((total+255)/256), dim3(256), 0, stream,
                             sent, emb, (float4*)XB, b0, sB*T, logT, Tm1, total);
          hipLaunchKernelGGL(k_gemm2, dim3(8, M/128, 2), dim3(256), 0, stream,
                             XF, XB, 304, 19, T, 0, 0, logT, Tm1,
                             wT0f, wT0b, b0f, b0b, xwF, xwB);
        } else {
          hipLaunchKernelGGL(k_gemm2, dim3(8, M/128, 2), dim3(256), 0, stream,
                             h0, h0, 512, 32, 512, sF*T, sB*T, logT, Tm1,
                             wT1f, wT1b, b1f, b1b, xwF, xwB);
        }
        {
          const float *xF = xwF, *xB = xwB, *wF = whF, *wB = whB;
          float* hop = layer ? h1s : h0;
          int hBs  = layer ? T*512 : 512*512;
          int tOF  = layer ? 0 : sF*T;
          int tOB  = layer ? 0 : sB*T;
          int Tk = T, ep = sl*T;
          float *hxp = hx, *hsp = hsave, *csp = csave; int *flp = flags;
          void* args[] = {(void*)&xF, (void*)&xB, (void*)&wF, (void*)&wB,
                          (void*)&hop, (void*)&hBs, (void*)&tOF, (void*)&tOB,
                          (void*)&Tk, (void*)&ep,
                          (void*)&hxp, (void*)&flp, (void*)&hsp, (void*)&csp};
          hipLaunchCooperativeKernel((const void*)k_lstm2s, dim3(C*4), dim3(512), args, 0, stream);
        }
        if (layer == 1){
          hipLaunchKernelGGL(k_feats_half, dim3(C*T/4), dim3(256), 0, stream,
                             h1s, fcw, fcb, feats, b0, logT, Tm1, sF*T, 0);
          hipLaunchKernelGGL(k_feats_half, dim3(C*T/4), dim3(256), 0, stream,
                             h1s, fcw, fcb, feats, b0, logT, Tm1, sB*T, 1);
        }
      }
    }
  }
  hipLaunchKernelGGL(k_viterbi, dim3(16), dim3(256), 0, stream, feats, trans, (float*)d_out);
}

// Round 2
// 6706.553 us; speedup vs baseline: 1.6819x; 1.6819x over previous
//
#include <hip/hip_runtime.h>
#include <cstddef>
#include <cstdint>
#include <math.h>

// B=64, T=512, V=50002, E=300, H=256, K=11, START=9, STOP=10
// Output: [64 score][64*512 path] floats = 32832.

__device__ __forceinline__ float sigmf_(float x){ return 1.0f/(1.0f+expf(-x)); }

// ---------------- generic zero ----------------
__global__ void k_zero(float* __restrict__ p, int n){
  for (int i = blockIdx.x*blockDim.x + threadIdx.x; i < n; i += gridDim.x*blockDim.x) p[i] = 0.f;
}

// ---------------- gather embeddings slab: X[C*T,304] zero-padded ----------------
__global__ void k_gather(const int* __restrict__ sent, const float* __restrict__ emb,
                         float4* __restrict__ X, int b0, int t0, int logT, int Tm1, int total){
  int idx = blockIdx.x*256 + threadIdx.x;
  if (idx >= total) return;
  int m = idx / 76, k4 = idx - m*76;
  int bl = m >> logT, t = m & Tm1;
  float4 v = make_float4(0.f,0.f,0.f,0.f);
  if (k4 < 75) v = ((const float4*)emb)[(size_t)sent[(size_t)(b0+bl)*512 + t0 + t]*75 + k4];
  X[idx] = v;
}

// ---------------- transpose w_ih into wT [dinPad,1024] (R5-proven) ----------------
__global__ void k_prepw(const float* __restrict__ w, float* __restrict__ wT, int din, int dinPad){
  int total = dinPad*1024;
  for (int idx = blockIdx.x*blockDim.x + threadIdx.x; idx < total; idx += gridDim.x*blockDim.x){
    int k = idx >> 10, n = idx & 1023;
    wT[idx] = (k < din) ? w[n*din + k] : 0.f;
  }
}

// ------- dual fp32 GEMM (z=0/1): C[M,1024] = A[M(strided rows),lda] @ Bm[K,1024] + bias -------
__global__ __launch_bounds__(256) void k_gemm2(
    const float* __restrict__ A0, const float* __restrict__ A1, int lda, int kTiles,
    int aBstride, int sOff0, int sOff1, int logT, int Tm1,
    const float* __restrict__ B0, const float* __restrict__ B1,
    const float* __restrict__ bias0, const float* __restrict__ bias1,
    float* __restrict__ C0, float* __restrict__ C1){
  __shared__ float As[16][132];
  __shared__ float Bs[16][132];
  const int z = blockIdx.z;
  const float* A   = z ? A1 : A0;
  const float* Bm  = z ? B1 : B0;
  const float* bias= z ? bias1 : bias0;
  float* Cc        = z ? C1 : C0;
  const int sOff   = z ? sOff1 : sOff0;
  const int t  = threadIdx.x;
  const int tx = t & 15, ty = t >> 4;
  const int m0 = blockIdx.y * 128, n0 = blockIdx.x * 128;
  const int arow = t >> 2, ak = (t & 3) * 4;
  const int brow = t >> 5, bc = (t & 31) * 4;
  const int gm0 = m0 + arow, gm1 = m0 + arow + 64;
  const size_t r0 = (size_t)(gm0 >> logT)*aBstride + sOff + (gm0 & Tm1);
  const size_t r1 = (size_t)(gm1 >> logT)*aBstride + sOff + (gm1 & Tm1);
  float acc[8][8] = {};
  for (int kt = 0; kt < kTiles; ++kt){
    const int kb = kt * 16;
    float4 a0 = *(const float4*)(A + r0*lda + kb + ak);
    float4 a1 = *(const float4*)(A + r1*lda + kb + ak);
    float4 b0 = *(const float4*)(Bm + (size_t)(kb+brow)*1024 + n0 + bc);
    float4 b1 = *(const float4*)(Bm + (size_t)(kb+brow+8)*1024 + n0 + bc);
    __syncthreads();
    As[ak+0][arow] = a0.x; As[ak+1][arow] = a0.y; As[ak+2][arow] = a0.z; As[ak+3][arow] = a0.w;
    As[ak+0][arow+64] = a1.x; As[ak+1][arow+64] = a1.y; As[ak+2][arow+64] = a1.z; As[ak+3][arow+64] = a1.w;
    *(float4*)&Bs[brow  ][bc] = b0;
    *(float4*)&Bs[brow+8][bc] = b1;
    __syncthreads();
    #pragma unroll
    for (int k = 0; k < 16; ++k){
      float av[8], bv[8];
      *(float4*)&av[0] = *(const float4*)&As[k][ty*8];
      *(float4*)&av[4] = *(const float4*)&As[k][ty*8+4];
      *(float4*)&bv[0] = *(const float4*)&Bs[k][tx*8];
      *(float4*)&bv[4] = *(const float4*)&Bs[k][tx*8+4];
      #pragma unroll
      for (int i = 0; i < 8; ++i)
        #pragma unroll
        for (int jj = 0; jj < 8; ++jj)
          acc[i][jj] = fmaf(av[i], bv[jj], acc[i][jj]);
    }
  }
  float bvals[8];
  *(float4*)&bvals[0] = *(const float4*)(bias + n0 + tx*8);
  *(float4*)&bvals[4] = *(const float4*)(bias + n0 + tx*8 + 4);
  float* Cp = Cc + (size_t)(m0 + ty*8)*1024 + n0 + tx*8;
  #pragma unroll
  for (int i = 0; i < 8; ++i){
    float4 o0 = make_float4(acc[i][0]+bvals[0], acc[i][1]+bvals[1], acc[i][2]+bvals[2], acc[i][3]+bvals[3]);
    float4 o1 = make_float4(acc[i][4]+bvals[4], acc[i][5]+bvals[5], acc[i][6]+bvals[6], acc[i][7]+bvals[7]);
    *(float4*)(Cp + (size_t)i*1024)     = o0;
    *(float4*)(Cp + (size_t)i*1024 + 4) = o1;
  }
}

// ---------------- LSTM recurrence: R2 fence-free protocol ----------------
// ROOT CAUSE FIX: agent-scope acquire/release atomics on gfx950 emit L2
// writeback/invalidate (per-XCD L2 is not cross-coherent) -> every step nuked
// the warm L2 (FETCH_SIZE ~= whole xw slab re-fetched from HBM; 19k cyc/step).
// New protocol uses ONLY relaxed agent atomics (coherent memops, no cache
// maintenance). Ordering is structural:
//   writer: relaxed h-stores -> __syncthreads (drains vmcnt) -> relaxed flag store
//   reader: relaxed flag poll (branch-dep) -> relaxed data load (always fresh)
// Dot product restructured: each thread owns ONE gate row, k split into
// local/remote 128-halves; local-half FMAs run while partner data is in
// flight. Bitwise-identical: each half accumulated in the old sequential
// order; final local+remote add commutes (matches old shfl_xor combine).
__global__ __launch_bounds__(512, 2) void k_lstm2s(
    const float* __restrict__ xwF, const float* __restrict__ xwB,
    const float* __restrict__ whhf, const float* __restrict__ whhb,
    float* __restrict__ hout, int hBstride, int tOffF, int tOffB,
    int T, int epoch,
    float* __restrict__ hx, int* __restrict__ flags,
    float* __restrict__ hsave, float* __restrict__ csave)
{
  __shared__ float hfull[256];
  __shared__ float gls[512];
  __shared__ float wtail[512*66];       // 135 KB: per-thread 64-float W tail
  const int blk = blockIdx.x;
  const int hh = (blk >> 3) & 1;                    // partner = blk ^ 8 (same XCD mod 8)
  const int chain = (blk & 7) | ((blk >> 4) << 3);  // bijection over [0, NB/2)
  const int b_local = chain >> 1;
  const int dir = chain & 1;
  const int t = threadIdx.x;
  // per-thread: gate row rK = t (global row gateK*256 + hh*128 + i0), full k=256
  const int gateK = t >> 7, i0 = t & 127;
  float4 wL[24], wR[24];
  {
    const float* whh = dir ? whhb : whhf;
    const float* base = whh + (size_t)(gateK*256 + hh*128 + i0)*256;
    const float* a = base + hh*128;        // local k-half (this block's h slice)
    const float* b = base + (1-hh)*128;    // remote k-half
    #pragma unroll
    for (int q = 0; q < 24; ++q){ wL[q] = *(const float4*)(a + q*4); wR[q] = *(const float4*)(b + q*4); }
    for (int q = 24; q < 32; ++q){
      #pragma unroll
      for (int e = 0; e < 4; ++e){
        wtail[t*66 + (q-24)*4 + e]      = a[q*4 + e];
        wtail[t*66 + 32 + (q-24)*4 + e] = b[q*4 + e];
      }
    }
  }
  if (t < 256) hfull[t] = hsave[chain*256 + t];
  float c = (t < 128) ? csave[chain*256 + hh*128 + t] : 0.f;
  __syncthreads();
  const int xcol = gateK*256 + hh*128 + i0;
  const float* xb = (dir ? xwB : xwF) + (size_t)b_local*T*1024 + xcol;
  float* hxme        = hx + (size_t)(chain*2 + hh)*256;        // [parity][128]
  const float* hxpt  = hx + (size_t)(chain*2 + (1-hh))*256;
  int* flg  = flags + (chain*2 + hh)*16;        // 64B-padded flags
  int* flgp = flags + (chain*2 + (1-hh))*16;
  const int tOff = dir ? tOffB : tOffF;
  float* hob = hout + (size_t)b_local*hBstride + dir*256 + hh*128;
  const float* wtb = &wtail[t*66];
  const float4* hL4 = ((const float4*)hfull) + hh*32;
  const float4* hR4 = ((const float4*)hfull) + (1-hh)*32;
  float xg = xb[(size_t)(dir ? (T-1) : 0)*1024];
  float hrem = 0.f;
  for (int s = 0; s < T; ++s){
    const int tt = dir ? (T-1-s) : s;
    float xn = 0.f;
    if (s < T-1) xn = xb[(size_t)(dir ? (T-2-s) : (s+1))*1024];   // prefetch
    if (s > 0 && t < 128) hfull[(1-hh)*128 + t] = hrem;  // remote h(s-1) -> LDS
    // ---- local-half partial (same sequential FMA order as old kap-half) ----
    float pa = 0.f;
    #pragma unroll
    for (int q = 0; q < 24; ++q){
      float4 hv = hL4[q];                       // wave-uniform -> LDS broadcast
      pa = fmaf(wL[q].x, hv.x, pa);
      pa = fmaf(wL[q].y, hv.y, pa);
      pa = fmaf(wL[q].z, hv.z, pa);
      pa = fmaf(wL[q].w, hv.w, pa);
    }
    #pragma unroll
    for (int q = 24; q < 32; ++q){
      float4 hv = hL4[q];
      const int o = (q-24)*4;
      pa = fmaf(wtb[o+0], hv.x, pa);
      pa = fmaf(wtb[o+1], hv.y, pa);
      pa = fmaf(wtb[o+2], hv.z, pa);
      pa = fmaf(wtb[o+3], hv.w, pa);
    }
    __syncthreads();                            // Ba: remote h visible in LDS
    // ---- remote-half partial ----
    float pb = 0.f;
    #pragma unroll
    for (int q = 0; q < 24; ++q){
      float4 hv = hR4[q];
      pb = fmaf(wR[q].x, hv.x, pb);
      pb = fmaf(wR[q].y, hv.y, pb);
      pb = fmaf(wR[q].z, hv.z, pb);
      pb = fmaf(wR[q].w, hv.w, pb);
    }
    #pragma unroll
    for (int q = 24; q < 32; ++q){
      float4 hv = hR4[q];
      const int o = (q-24)*4;
      pb = fmaf(wtb[32+o+0], hv.x, pb);
      pb = fmaf(wtb[32+o+1], hv.y, pb);
      pb = fmaf(wtb[32+o+2], hv.z, pb);
      pb = fmaf(wtb[32+o+3], hv.w, pb);
    }
    float acc = (pa + pb) + xg;                 // == old (sum_k0+sum_k1)+xg bitwise
    float act = (gateK == 2) ? tanhf(acc) : sigmf_(acc);   // i,f,o sigmoid; g tanh
    gls[t] = act;
    __syncthreads();                            // B1: gates ready
    float hval = 0.f;
    if (t < 128){
      c = gls[128 + t]*c + gls[t]*gls[256 + t];
      hval = gls[384 + t]*tanhf(c);
      hfull[hh*128 + t] = hval;
      __hip_atomic_store(&hxme[(s & 1)*128 + t], hval,
                         __ATOMIC_RELAXED, __HIP_MEMORY_SCOPE_AGENT);
    }
    __syncthreads();                            // B2: h-stores drained (vmcnt 0)
    if (t == 0)
      __hip_atomic_store(flg, epoch + s + 1, __ATOMIC_RELAXED, __HIP_MEMORY_SCOPE_AGENT);
    if (t < 128){
      hob[(size_t)(tOff + tt)*512 + t] = hval;  // plain store, poll shadow
      if (s < T-1){
        int lim = 0;                            // bounded spin (hang fuse)
        while (__hip_atomic_load(flgp, __ATOMIC_RELAXED, __HIP_MEMORY_SCOPE_AGENT) < epoch + s + 1
               && ++lim < (1<<20)) {}
        hrem = __hip_atomic_load(&hxpt[(s & 1)*128 + t],
                                 __ATOMIC_RELAXED, __HIP_MEMORY_SCOPE_AGENT);
      }
    }
    xg = xn;
  }
  if (t < 128){
    hsave[chain*256 + hh*128 + t] = hfull[hh*128 + t];
    csave[chain*256 + hh*128 + t] = c;
  }
}

// ---------------- feats accumulation (one dir half per call; R5-proven) ----------------
__global__ __launch_bounds__(256) void k_feats_half(
    const float* __restrict__ h1s, const float* __restrict__ fcw, const float* __restrict__ fcb,
    float* __restrict__ feats, int b0, int logT, int Tm1, int tG0, int dir){
  int wv = threadIdx.x >> 6, lane = threadIdx.x & 63;
  int m = blockIdx.x*4 + wv;                 // m = bl*T + tl
  const float4* row = (const float4*)(h1s + (size_t)m*512 + dir*256);
  float4 rv = row[lane];
  int bl = m >> logT, tl = m & Tm1;
  size_t fbase = ((size_t)(b0 + bl)*512 + tG0 + tl)*11;
  #pragma unroll
  for (int n = 0; n < 11; ++n){
    const float4* wr = (const float4*)(fcw + n*512 + dir*256);
    float4 w4 = wr[lane];
    float p = rv.x*w4.x + rv.y*w4.y + rv.z*w4.z + rv.w*w4.w;
    #pragma unroll
    for (int off = 32; off > 0; off >>= 1) p += __shfl_down(p, off, 64);
    if (lane == 0){
      float add = (dir == 0) ? (p + fcb[n]) : p;
      feats[fbase + n] += add;
    }
  }
}

// ---------------- Viterbi: 1 wave per batch (R2/R5-proven) ----------------
__global__ __launch_bounds__(256) void k_viterbi(const float* __restrict__ feats,
                        const float* __restrict__ trans, float* __restrict__ out){
  __shared__ unsigned char bp[4][512][12];
  const int wave = threadIdx.x >> 6, lane = threadIdx.x & 63;
  const int b = blockIdx.x*4 + wave;
  const int j = lane;
  float tr[11];
  float fv;
  if (j < 11){
    #pragma unroll
    for (int p = 0; p < 11; ++p) tr[p] = trans[j*11 + p];
    fv = (j == 9) ? 0.f : -1000.f;
  } else {
    #pragma unroll
    for (int p = 0; p < 11; ++p) tr[p] = -1e30f;
    fv = -1e30f;
  }
  for (int t = 0; t < 512; ++t){
    float best = -1e38f; int bestp = 0;
    #pragma unroll
    for (int p = 0; p < 11; ++p){
      float v = __shfl(fv, p, 64) + tr[p];
      if (v > best){ best = v; bestp = p; }   // strict > keeps FIRST max (np.argmax)
    }
    float feat = (j < 11) ? feats[((size_t)b*512 + t)*11 + j] : 0.f;
    fv = best + feat;
    if (j < 11) bp[wave][t][j] = (unsigned char)bestp;
  }
  float term = (j < 11) ? fv + trans[10*11 + j] : -1e38f;
  float best = -1e38f; int bestp = 0;
  #pragma unroll
  for (int p = 0; p < 11; ++p){
    float v = __shfl(term, p, 64);
    if (v > best){ best = v; bestp = p; }
  }
  if (lane == 0){
    out[b] = best;
    float* path = out + 64 + (size_t)b*512;
    int cur = bestp;
    path[511] = (float)cur;
    for (int t = 511; t >= 1; --t){
      cur = bp[wave][t][cur];
      path[t-1] = (float)cur;
    }
  }
}

extern "C" void kernel_launch(void* const* d_in, const int* in_sizes, int n_in,
                              void* d_out, int out_size, void* d_ws, size_t ws_size,
                              hipStream_t stream){
  const int*   sent  = (const int*)d_in[0];
  const float* emb   = (const float*)d_in[2];
  const float* fcw   = (const float*)d_in[3];
  const float* fcb   = (const float*)d_in[4];
  const float* trans = (const float*)d_in[5];
  const float* wih0f = (const float*)d_in[6];
  const float* whh0f = (const float*)d_in[7];
  const float* b0f   = (const float*)d_in[8];
  const float* wih0b = (const float*)d_in[9];
  const float* whh0b = (const float*)d_in[10];
  const float* b0b   = (const float*)d_in[11];
  const float* wih1f = (const float*)d_in[12];
  const float* whh1f = (const float*)d_in[13];
  const float* b1f   = (const float*)d_in[14];
  const float* wih1b = (const float*)d_in[15];
  const float* whh1b = (const float*)d_in[16];
  const float* b1b   = (const float*)d_in[17];

  float* ws = (float*)d_ws;
  // -------- fixed region (flags 64B-padded: 4096 ints) --------
  const size_t o_wT0f = 0;                         // 304*1024
  const size_t o_wT0b = o_wT0f + 311296;
  const size_t o_wT1f = o_wT0b + 311296;           // 512*1024
  const size_t o_wT1b = o_wT1f + 524288;
  const size_t o_hx   = o_wT1b + 524288;           // 64*2 chains*2 hh*2 par*128 = 65536
  const size_t o_flag = o_hx   + 65536;            // 4096 ints
  const size_t o_hs   = o_flag + 4096;             // hsave 32768
  const size_t o_cs   = o_hs   + 32768;            // csave 32768
  const size_t o_feat = o_cs   + 32768;            // 32768*11 = 360448
  const size_t o_var  = o_feat + 360448;
  float* wT0f = ws + o_wT0f;
  float* wT0b = ws + o_wT0b;
  float* wT1f = ws + o_wT1f;
  float* wT1b = ws + o_wT1b;
  float* hx    = ws + o_hx;
  int*   flags = (int*)(ws + o_flag);
  float* hsave = ws + o_hs;
  float* csave = ws + o_cs;
  float* feats = ws + o_feat;

  // -------- adaptive (C batches, T timesteps) slab sizing --------
  int C = 8, T = 32, logT = 5;
  {
    const int cc[8]  = {64, 64, 32, 32, 16, 16, 8, 8};
    const int tt[8]  = {32, 16, 32, 16, 32, 16, 64, 32};
    const int lt[8]  = { 5,  4,  5,  4,  5,  4,  6,  5};
    for (int i = 0; i < 8; ++i){
      size_t need = (o_var + (size_t)cc[i]*tt[i]*2656 + (size_t)cc[i]*262144)*4;
      if (need <= ws_size){ C = cc[i]; T = tt[i]; logT = lt[i]; break; }
    }
  }
  const int Tm1 = T - 1, S = 512 / T;
  float* XF  = ws + o_var;                        // [C*T,304]  (layer0)
  float* XB  = XF + (size_t)C*T*304;
  float* xwF = XB + (size_t)C*T*304;              // [C*T,1024]
  float* xwB = xwF + (size_t)C*T*1024;
  float* h0  = xwB + (size_t)C*T*1024;            // [C,512,512] fp32
  float* h1s = XF;                                // alias: [C,T,512] (layer1 slab)

  hipLaunchKernelGGL(k_prepw, dim3(512), dim3(256), 0, stream, wih0f, wT0f, 300, 304);
  hipLaunchKernelGGL(k_prepw, dim3(512), dim3(256), 0, stream, wih0b, wT0b, 300, 304);
  hipLaunchKernelGGL(k_prepw, dim3(512), dim3(256), 0, stream, wih1f, wT1f, 512, 512);
  hipLaunchKernelGGL(k_prepw, dim3(512), dim3(256), 0, stream, wih1b, wT1b, 512, 512);
  hipLaunchKernelGGL(k_zero,  dim3(512), dim3(256), 0, stream, feats, 360448);

  for (int b0 = 0; b0 < 64; b0 += C){
    for (int layer = 0; layer < 2; ++layer){
      hipLaunchKernelGGL(k_zero, dim3(256), dim3(256), 0, stream, ws + o_hx, 65536 + 4096 + 65536);
      const float* whF = layer ? whh1f : whh0f;
      const float* whB = layer ? whh1b : whh0b;
      for (int sl = 0; sl < S; ++sl){
        const int sF = sl, sB = S - 1 - sl;
        const int M = C*T;
        if (layer == 0){
          int total = C*T*76;
          hipLaunchKernelGGL(k_gather, dim3((total+255)/256), dim3(256), 0, stream,
                             sent, emb, (float4*)XF, b0, sF*T, logT, Tm1, total);
          hipLaunchKernelGGL(k_gather, dim3((total+255)/256), dim3(256), 0, stream,
                             sent, emb, (float4*)XB, b0, sB*T, logT, Tm1, total);
          hipLaunchKernelGGL(k_gemm2, dim3(8, M/128, 2), dim3(256), 0, stream,
                             XF, XB, 304, 19, T, 0, 0, logT, Tm1,
                             wT0f, wT0b, b0f, b0b, xwF, xwB);
        } else {
          hipLaunchKernelGGL(k_gemm2, dim3(8, M/128, 2), dim3(256), 0, stream,
                             h0, h0, 512, 32, 512, sF*T, sB*T, logT, Tm1,
                             wT1f, wT1b, b1f, b1b, xwF, xwB);
        }
        {
          const float *xF = xwF, *xB = xwB, *wF = whF, *wB = whB;
          float* hop = layer ? h1s : h0;
          int hBs  = layer ? T*512 : 512*512;
          int tOF  = layer ? 0 : sF*T;
          int tOB  = layer ? 0 : sB*T;
          int Tk = T, ep = sl*T;
          float *hxp = hx, *hsp = hsave, *csp = csave; int *flp = flags;
          void* args[] = {(void*)&xF, (void*)&xB, (void*)&wF, (void*)&wB,
                          (void*)&hop, (void*)&hBs, (void*)&tOF, (void*)&tOB,
                          (void*)&Tk, (void*)&ep,
                          (void*)&hxp, (void*)&flp, (void*)&hsp, (void*)&csp};
          hipLaunchCooperativeKernel((const void*)k_lstm2s, dim3(C*4), dim3(512), args, 0, stream);
        }
        if (layer == 1){
          hipLaunchKernelGGL(k_feats_half, dim3(C*T/4), dim3(256), 0, stream,
                             h1s, fcw, fcb, feats, b0, logT, Tm1, sF*T, 0);
          hipLaunchKernelGGL(k_feats_half, dim3(C*T/4), dim3(256), 0, stream,
                             h1s, fcw, fcb, feats, b0, logT, Tm1, sB*T, 1);
        }
      }
    }
  }
  hipLaunchKernelGGL(k_viterbi, dim3(16), dim3(256), 0, stream, feats, trans, (float*)d_out);
}

// Round 3
// 5634.524 us; speedup vs baseline: 2.0019x; 1.1903x over previous
//
#include <hip/hip_runtime.h>
#include <cstddef>
#include <cstdint>
#include <math.h>

// B=64, T=512, V=50002, E=300, H=256, K=11, START=9, STOP=10
// Output: [64 score][64*512 path] floats = 32832.

__device__ __forceinline__ float sigmf_(float x){ return 1.0f/(1.0f+expf(-x)); }

// ---------------- generic zero ----------------
__global__ void k_zero(float* __restrict__ p, int n){
  for (int i = blockIdx.x*blockDim.x + threadIdx.x; i < n; i += gridDim.x*blockDim.x) p[i] = 0.f;
}

// ---------------- gather embeddings slab: X[C*T,304] zero-padded ----------------
__global__ void k_gather(const int* __restrict__ sent, const float* __restrict__ emb,
                         float4* __restrict__ X, int b0, int t0, int logT, int Tm1, int total){
  int idx = blockIdx.x*256 + threadIdx.x;
  if (idx >= total) return;
  int m = idx / 76, k4 = idx - m*76;
  int bl = m >> logT, t = m & Tm1;
  float4 v = make_float4(0.f,0.f,0.f,0.f);
  if (k4 < 75) v = ((const float4*)emb)[(size_t)sent[(size_t)(b0+bl)*512 + t0 + t]*75 + k4];
  X[idx] = v;
}

// ---------------- transpose w_ih into wT [dinPad,1024] ----------------
__global__ void k_prepw(const float* __restrict__ w, float* __restrict__ wT, int din, int dinPad){
  int total = dinPad*1024;
  for (int idx = blockIdx.x*blockDim.x + threadIdx.x; idx < total; idx += gridDim.x*blockDim.x){
    int k = idx >> 10, n = idx & 1023;
    wT[idx] = (k < din) ? w[n*din + k] : 0.f;
  }
}

// ------- dual fp32 GEMM (z=0/1): C[M,1024] = A[M(strided rows),lda] @ Bm[K,1024] + bias -------
__global__ __launch_bounds__(256) void k_gemm2(
    const float* __restrict__ A0, const float* __restrict__ A1, int lda, int kTiles,
    int aBstride, int sOff0, int sOff1, int logT, int Tm1,
    const float* __restrict__ B0, const float* __restrict__ B1,
    const float* __restrict__ bias0, const float* __restrict__ bias1,
    float* __restrict__ C0, float* __restrict__ C1){
  __shared__ float As[16][132];
  __shared__ float Bs[16][132];
  const int z = blockIdx.z;
  const float* A   = z ? A1 : A0;
  const float* Bm  = z ? B1 : B0;
  const float* bias= z ? bias1 : bias0;
  float* Cc        = z ? C1 : C0;
  const int sOff   = z ? sOff1 : sOff0;
  const int t  = threadIdx.x;
  const int tx = t & 15, ty = t >> 4;
  const int m0 = blockIdx.y * 128, n0 = blockIdx.x * 128;
  const int arow = t >> 2, ak = (t & 3) * 4;
  const int brow = t >> 5, bc = (t & 31) * 4;
  const int gm0 = m0 + arow, gm1 = m0 + arow + 64;
  const size_t r0 = (size_t)(gm0 >> logT)*aBstride + sOff + (gm0 & Tm1);
  const size_t r1 = (size_t)(gm1 >> logT)*aBstride + sOff + (gm1 & Tm1);
  float acc[8][8] = {};
  for (int kt = 0; kt < kTiles; ++kt){
    const int kb = kt * 16;
    float4 a0 = *(const float4*)(A + r0*lda + kb + ak);
    float4 a1 = *(const float4*)(A + r1*lda + kb + ak);
    float4 b0 = *(const float4*)(Bm + (size_t)(kb+brow)*1024 + n0 + bc);
    float4 b1 = *(const float4*)(Bm + (size_t)(kb+brow+8)*1024 + n0 + bc);
    __syncthreads();
    As[ak+0][arow] = a0.x; As[ak+1][arow] = a0.y; As[ak+2][arow] = a0.z; As[ak+3][arow] = a0.w;
    As[ak+0][arow+64] = a1.x; As[ak+1][arow+64] = a1.y; As[ak+2][arow+64] = a1.z; As[ak+3][arow+64] = a1.w;
    *(float4*)&Bs[brow  ][bc] = b0;
    *(float4*)&Bs[brow+8][bc] = b1;
    __syncthreads();
    #pragma unroll
    for (int k = 0; k < 16; ++k){
      float av[8], bv[8];
      *(float4*)&av[0] = *(const float4*)&As[k][ty*8];
      *(float4*)&av[4] = *(const float4*)&As[k][ty*8+4];
      *(float4*)&bv[0] = *(const float4*)&Bs[k][tx*8];
      *(float4*)&bv[4] = *(const float4*)&Bs[k][tx*8+4];
      #pragma unroll
      for (int i = 0; i < 8; ++i)
        #pragma unroll
        for (int jj = 0; jj < 8; ++jj)
          acc[i][jj] = fmaf(av[i], bv[jj], acc[i][jj]);
    }
  }
  float bvals[8];
  *(float4*)&bvals[0] = *(const float4*)(bias + n0 + tx*8);
  *(float4*)&bvals[4] = *(const float4*)(bias + n0 + tx*8 + 4);
  float* Cp = Cc + (size_t)(m0 + ty*8)*1024 + n0 + tx*8;
  #pragma unroll
  for (int i = 0; i < 8; ++i){
    float4 o0 = make_float4(acc[i][0]+bvals[0], acc[i][1]+bvals[1], acc[i][2]+bvals[2], acc[i][3]+bvals[3]);
    float4 o1 = make_float4(acc[i][4]+bvals[4], acc[i][5]+bvals[5], acc[i][6]+bvals[6], acc[i][7]+bvals[7]);
    *(float4*)(Cp + (size_t)i*1024)     = o0;
    *(float4*)(Cp + (size_t)i*1024 + 4) = o1;
  }
}

// ---------------- LSTM recurrence: R3 = R2 protocol + spill pin + lean exchange ----------------
// DELTA vs R2 (math/FMA order byte-identical -> bitwise-same results):
//  1) amdgpu_waves_per_eu(2,2): pin 2 waves/SIMD so the allocator uses the full
//     256-VGPR budget for the 48 live float4 weights (R2 reported 128 VGPR ->
//     forced spills). LDS (138KB) already limits to 1 block/CU, so no occupancy cost.
//  2) single-lane flag poll (t==0 only): R2 had 128 lanes hammering ONE flag word
//     with agent atomics (uncoalescable same-address ops, serialized at the
//     coherence point). Wave0 lanes wait implicitly (same wave, no barrier).
//  3) partner-h loads packed as 64 x 8B relaxed atomic loads by wave0 (was 128 x 4B
//     by two waves); wave0 also writes the LDS remote half.
__global__ __launch_bounds__(512) __attribute__((amdgpu_waves_per_eu(2, 2)))
void k_lstm2s(
    const float* __restrict__ xwF, const float* __restrict__ xwB,
    const float* __restrict__ whhf, const float* __restrict__ whhb,
    float* __restrict__ hout, int hBstride, int tOffF, int tOffB,
    int T, int epoch,
    float* __restrict__ hx, int* __restrict__ flags,
    float* __restrict__ hsave, float* __restrict__ csave)
{
  __shared__ float hfull[256];
  __shared__ float gls[512];
  __shared__ float wtail[512*66];       // 135 KB: per-thread 64-float W tail
  const int blk = blockIdx.x;
  const int hh = (blk >> 3) & 1;                    // partner = blk ^ 8 (same XCD mod 8)
  const int chain = (blk & 7) | ((blk >> 4) << 3);  // bijection over [0, NB/2)
  const int b_local = chain >> 1;
  const int dir = chain & 1;
  const int t = threadIdx.x;
  // per-thread: gate row (gateK*256 + hh*128 + i0), full k=256 split local/remote
  const int gateK = t >> 7, i0 = t & 127;
  float4 wL[24], wR[24];
  {
    const float* whh = dir ? whhb : whhf;
    const float* base = whh + (size_t)(gateK*256 + hh*128 + i0)*256;
    const float* a = base + hh*128;        // local k-half (this block's h slice)
    const float* b = base + (1-hh)*128;    // remote k-half
    #pragma unroll
    for (int q = 0; q < 24; ++q){ wL[q] = *(const float4*)(a + q*4); wR[q] = *(const float4*)(b + q*4); }
    for (int q = 24; q < 32; ++q){
      #pragma unroll
      for (int e = 0; e < 4; ++e){
        wtail[t*66 + (q-24)*4 + e]      = a[q*4 + e];
        wtail[t*66 + 32 + (q-24)*4 + e] = b[q*4 + e];
      }
    }
  }
  if (t < 256) hfull[t] = hsave[chain*256 + t];
  float c = (t < 128) ? csave[chain*256 + hh*128 + t] : 0.f;
  __syncthreads();
  const int xcol = gateK*256 + hh*128 + i0;
  const float* xb = (dir ? xwB : xwF) + (size_t)b_local*T*1024 + xcol;
  float* hxme        = hx + (size_t)(chain*2 + hh)*256;        // [parity][128]
  const float* hxpt  = hx + (size_t)(chain*2 + (1-hh))*256;
  int* flg  = flags + (chain*2 + hh)*16;        // 64B-padded flags
  int* flgp = flags + (chain*2 + (1-hh))*16;
  const int tOff = dir ? tOffB : tOffF;
  float* hob = hout + (size_t)b_local*hBstride + dir*256 + hh*128;
  const float* wtb = &wtail[t*66];
  const float4* hL4 = ((const float4*)hfull) + hh*32;
  const float4* hR4 = ((const float4*)hfull) + (1-hh)*32;
  float xg = xb[(size_t)(dir ? (T-1) : 0)*1024];
  float2 hrem = make_float2(0.f, 0.f);
  for (int s = 0; s < T; ++s){
    const int tt = dir ? (T-1-s) : s;
    float xn = 0.f;
    if (s < T-1) xn = xb[(size_t)(dir ? (T-2-s) : (s+1))*1024];   // prefetch
    if (s > 0 && t < 64){                       // wave0: remote h(s-1) pair -> LDS
      hfull[(1-hh)*128 + 2*t]     = hrem.x;
      hfull[(1-hh)*128 + 2*t + 1] = hrem.y;
    }
    // ---- local-half partial (same sequential FMA order as R2) ----
    float pa = 0.f;
    #pragma unroll
    for (int q = 0; q < 24; ++q){
      float4 hv = hL4[q];                       // wave-uniform -> LDS broadcast
      pa = fmaf(wL[q].x, hv.x, pa);
      pa = fmaf(wL[q].y, hv.y, pa);
      pa = fmaf(wL[q].z, hv.z, pa);
      pa = fmaf(wL[q].w, hv.w, pa);
    }
    #pragma unroll
    for (int q = 24; q < 32; ++q){
      float4 hv = hL4[q];
      const int o = (q-24)*4;
      pa = fmaf(wtb[o+0], hv.x, pa);
      pa = fmaf(wtb[o+1], hv.y, pa);
      pa = fmaf(wtb[o+2], hv.z, pa);
      pa = fmaf(wtb[o+3], hv.w, pa);
    }
    __syncthreads();                            // Ba: remote h visible in LDS
    // ---- remote-half partial ----
    float pb = 0.f;
    #pragma unroll
    for (int q = 0; q < 24; ++q){
      float4 hv = hR4[q];
      pb = fmaf(wR[q].x, hv.x, pb);
      pb = fmaf(wR[q].y, hv.y, pb);
      pb = fmaf(wR[q].z, hv.z, pb);
      pb = fmaf(wR[q].w, hv.w, pb);
    }
    #pragma unroll
    for (int q = 24; q < 32; ++q){
      float4 hv = hR4[q];
      const int o = (q-24)*4;
      pb = fmaf(wtb[32+o+0], hv.x, pb);
      pb = fmaf(wtb[32+o+1], hv.y, pb);
      pb = fmaf(wtb[32+o+2], hv.z, pb);
      pb = fmaf(wtb[32+o+3], hv.w, pb);
    }
    float acc = (pa + pb) + xg;                 // == R2 bitwise
    float act = (gateK == 2) ? tanhf(acc) : sigmf_(acc);   // i,f,o sigmoid; g tanh
    gls[t] = act;
    __syncthreads();                            // B1: gates ready
    float hval = 0.f;
    if (t < 128){
      c = gls[128 + t]*c + gls[t]*gls[256 + t];
      hval = gls[384 + t]*tanhf(c);
      hfull[hh*128 + t] = hval;
      __hip_atomic_store(&hxme[(s & 1)*128 + t], hval,
                         __ATOMIC_RELAXED, __HIP_MEMORY_SCOPE_AGENT);
    }
    __syncthreads();                            // B2: all h-stores drained (vmcnt 0)
    if (t == 0)
      __hip_atomic_store(flg, epoch + s + 1, __ATOMIC_RELAXED, __HIP_MEMORY_SCOPE_AGENT);
    if (t < 128) hob[(size_t)(tOff + tt)*512 + t] = hval;  // plain store, poll shadow
    if (s < T-1){
      if (t == 0){                              // single-lane poll (no same-addr hammering)
        int lim = 0;
        while (__hip_atomic_load(flgp, __ATOMIC_RELAXED, __HIP_MEMORY_SCOPE_AGENT) < epoch + s + 1
               && ++lim < (1<<20)) {}
      }
      if (t < 64){                              // wave0: packed 8B partner loads
        union { unsigned long long u; float2 f; } uu;
        uu.u = __hip_atomic_load((const unsigned long long*)(hxpt + (s & 1)*128 + 2*t),
                                 __ATOMIC_RELAXED, __HIP_MEMORY_SCOPE_AGENT);
        hrem = uu.f;
      }
    }
    xg = xn;
  }
  if (t < 128){
    hsave[chain*256 + hh*128 + t] = hfull[hh*128 + t];
    csave[chain*256 + hh*128 + t] = c;
  }
}

// ---------------- feats accumulation (one dir half per call) ----------------
__global__ __launch_bounds__(256) void k_feats_half(
    const float* __restrict__ h1s, const float* __restrict__ fcw, const float* __restrict__ fcb,
    float* __restrict__ feats, int b0, int logT, int Tm1, int tG0, int dir){
  int wv = threadIdx.x >> 6, lane = threadIdx.x & 63;
  int m = blockIdx.x*4 + wv;                 // m = bl*T + tl
  const float4* row = (const float4*)(h1s + (size_t)m*512 + dir*256);
  float4 rv = row[lane];
  int bl = m >> logT, tl = m & Tm1;
  size_t fbase = ((size_t)(b0 + bl)*512 + tG0 + tl)*11;
  #pragma unroll
  for (int n = 0; n < 11; ++n){
    const float4* wr = (const float4*)(fcw + n*512 + dir*256);
    float4 w4 = wr[lane];
    float p = rv.x*w4.x + rv.y*w4.y + rv.z*w4.z + rv.w*w4.w;
    #pragma unroll
    for (int off = 32; off > 0; off >>= 1) p += __shfl_down(p, off, 64);
    if (lane == 0){
      float add = (dir == 0) ? (p + fcb[n]) : p;
      feats[fbase + n] += add;
    }
  }
}

// ---------------- Viterbi: 1 wave per batch + 4-deep feats prefetch ----------------
// The 512-step recurrence is serial through an 11-shfl chain (~150cyc), but the
// feats load is independent -> prefetch 4 steps ahead in statically-indexed regs
// (rule #20: no runtime-indexed arrays) to hide the ~L3 latency.
__global__ __launch_bounds__(256) void k_viterbi(const float* __restrict__ feats,
                        const float* __restrict__ trans, float* __restrict__ out){
  __shared__ unsigned char bp[4][512][12];
  const int wave = threadIdx.x >> 6, lane = threadIdx.x & 63;
  const int b = blockIdx.x*4 + wave;
  const int j = lane;
  float tr[11];
  float fv;
  if (j < 11){
    #pragma unroll
    for (int p = 0; p < 11; ++p) tr[p] = trans[j*11 + p];
    fv = (j == 9) ? 0.f : -1000.f;
  } else {
    #pragma unroll
    for (int p = 0; p < 11; ++p) tr[p] = -1e30f;
    fv = -1e30f;
  }
  const float* fb = feats + ((size_t)b*512)*11 + j;
  float f0 = (j < 11) ? fb[0*11] : 0.f;
  float f1 = (j < 11) ? fb[1*11] : 0.f;
  float f2 = (j < 11) ? fb[2*11] : 0.f;
  float f3 = (j < 11) ? fb[3*11] : 0.f;
#define VSTEP(TT, FREG) {                                            \
    float best = -1e38f; int bestp = 0;                              \
    _Pragma("unroll")                                                \
    for (int p = 0; p < 11; ++p){                                    \
      float v = __shfl(fv, p, 64) + tr[p];                           \
      if (v > best){ best = v; bestp = p; }                          \
    }                                                                \
    fv = best + FREG;                                                \
    if (j < 11) bp[wave][TT][j] = (unsigned char)bestp; }
  for (int t = 0; t < 512; t += 4){
    VSTEP(t+0, f0); f0 = (j < 11 && t+4 < 512) ? fb[(size_t)(t+4)*11] : 0.f;
    VSTEP(t+1, f1); f1 = (j < 11 && t+5 < 512) ? fb[(size_t)(t+5)*11] : 0.f;
    VSTEP(t+2, f2); f2 = (j < 11 && t+6 < 512) ? fb[(size_t)(t+6)*11] : 0.f;
    VSTEP(t+3, f3); f3 = (j < 11 && t+7 < 512) ? fb[(size_t)(t+7)*11] : 0.f;
  }
#undef VSTEP
  float term = (j < 11) ? fv + trans[10*11 + j] : -1e38f;
  float best = -1e38f; int bestp = 0;
  #pragma unroll
  for (int p = 0; p < 11; ++p){
    float v = __shfl(term, p, 64);
    if (v > best){ best = v; bestp = p; }
  }
  if (lane == 0){
    out[b] = best;
    float* path = out + 64 + (size_t)b*512;
    int cur = bestp;
    path[511] = (float)cur;
    for (int t = 511; t >= 1; --t){
      cur = bp[wave][t][cur];
      path[t-1] = (float)cur;
    }
  }
}

extern "C" void kernel_launch(void* const* d_in, const int* in_sizes, int n_in,
                              void* d_out, int out_size, void* d_ws, size_t ws_size,
                              hipStream_t stream){
  const int*   sent  = (const int*)d_in[0];
  const float* emb   = (const float*)d_in[2];
  const float* fcw   = (const float*)d_in[3];
  const float* fcb   = (const float*)d_in[4];
  const float* trans = (const float*)d_in[5];
  const float* wih0f = (const float*)d_in[6];
  const float* whh0f = (const float*)d_in[7];
  const float* b0f   = (const float*)d_in[8];
  const float* wih0b = (const float*)d_in[9];
  const float* whh0b = (const float*)d_in[10];
  const float* b0b   = (const float*)d_in[11];
  const float* wih1f = (const float*)d_in[12];
  const float* whh1f = (const float*)d_in[13];
  const float* b1f   = (const float*)d_in[14];
  const float* wih1b = (const float*)d_in[15];
  const float* whh1b = (const float*)d_in[16];
  const float* b1b   = (const float*)d_in[17];

  float* ws = (float*)d_ws;
  // -------- fixed region (flags 64B-padded: 4096 ints) --------
  const size_t o_wT0f = 0;                         // 304*1024
  const size_t o_wT0b = o_wT0f + 311296;
  const size_t o_wT1f = o_wT0b + 311296;           // 512*1024
  const size_t o_wT1b = o_wT1f + 524288;
  const size_t o_hx   = o_wT1b + 524288;           // 64*2 chains*2 hh*2 par*128 = 65536
  const size_t o_flag = o_hx   + 65536;            // 4096 ints
  const size_t o_hs   = o_flag + 4096;             // hsave 32768
  const size_t o_cs   = o_hs   + 32768;            // csave 32768
  const size_t o_feat = o_cs   + 32768;            // 32768*11 = 360448
  const size_t o_var  = o_feat + 360448;
  float* wT0f = ws + o_wT0f;
  float* wT0b = ws + o_wT0b;
  float* wT1f = ws + o_wT1f;
  float* wT1b = ws + o_wT1b;
  float* hx    = ws + o_hx;
  int*   flags = (int*)(ws + o_flag);
  float* hsave = ws + o_hs;
  float* csave = ws + o_cs;
  float* feats = ws + o_feat;

  // -------- adaptive (C batches, T timesteps) slab sizing --------
  // (64,64) first: halves lstm/gemm dispatch count, M=4096 GEMMs; falls back safely.
  int C = 8, T = 32, logT = 5;
  {
    const int cc[9]  = {64, 64, 64, 32, 32, 16, 16, 8, 8};
    const int tt[9]  = {64, 32, 16, 32, 16, 32, 16, 64, 32};
    const int lt[9]  = { 6,  5,  4,  5,  4,  5,  4,  6,  5};
    for (int i = 0; i < 9; ++i){
      size_t need = (o_var + (size_t)cc[i]*tt[i]*2656 + (size_t)cc[i]*262144)*4;
      if (need <= ws_size){ C = cc[i]; T = tt[i]; logT = lt[i]; break; }
    }
  }
  const int Tm1 = T - 1, S = 512 / T;
  float* XF  = ws + o_var;                        // [C*T,304]  (layer0)
  float* XB  = XF + (size_t)C*T*304;
  float* xwF = XB + (size_t)C*T*304;              // [C*T,1024]
  float* xwB = xwF + (size_t)C*T*1024;
  float* h0  = xwB + (size_t)C*T*1024;            // [C,512,512] fp32
  float* h1s = XF;                                // alias: [C,T,512] (layer1 slab)

  hipLaunchKernelGGL(k_prepw, dim3(512), dim3(256), 0, stream, wih0f, wT0f, 300, 304);
  hipLaunchKernelGGL(k_prepw, dim3(512), dim3(256), 0, stream, wih0b, wT0b, 300, 304);
  hipLaunchKernelGGL(k_prepw, dim3(512), dim3(256), 0, stream, wih1f, wT1f, 512, 512);
  hipLaunchKernelGGL(k_prepw, dim3(512), dim3(256), 0, stream, wih1b, wT1b, 512, 512);
  hipLaunchKernelGGL(k_zero,  dim3(512), dim3(256), 0, stream, feats, 360448);

  for (int b0 = 0; b0 < 64; b0 += C){
    for (int layer = 0; layer < 2; ++layer){
      hipLaunchKernelGGL(k_zero, dim3(256), dim3(256), 0, stream, ws + o_hx, 65536 + 4096 + 65536);
      const float* whF = layer ? whh1f : whh0f;
      const float* whB = layer ? whh1b : whh0b;
      for (int sl = 0; sl < S; ++sl){
        const int sF = sl, sB = S - 1 - sl;
        const int M = C*T;
        if (layer == 0){
          int total = C*T*76;
          hipLaunchKernelGGL(k_gather, dim3((total+255)/256), dim3(256), 0, stream,
                             sent, emb, (float4*)XF, b0, sF*T, logT, Tm1, total);
          hipLaunchKernelGGL(k_gather, dim3((total+255)/256), dim3(256), 0, stream,
                             sent, emb, (float4*)XB, b0, sB*T, logT, Tm1, total);
          hipLaunchKernelGGL(k_gemm2, dim3(8, M/128, 2), dim3(256), 0, stream,
                             XF, XB, 304, 19, T, 0, 0, logT, Tm1,
                             wT0f, wT0b, b0f, b0b, xwF, xwB);
        } else {
          hipLaunchKernelGGL(k_gemm2, dim3(8, M/128, 2), dim3(256), 0, stream,
                             h0, h0, 512, 32, 512, sF*T, sB*T, logT, Tm1,
                             wT1f, wT1b, b1f, b1b, xwF, xwB);
        }
        {
          const float *xF = xwF, *xB = xwB, *wF = whF, *wB = whB;
          float* hop = layer ? h1s : h0;
          int hBs  = layer ? T*512 : 512*512;
          int tOF  = layer ? 0 : sF*T;
          int tOB  = layer ? 0 : sB*T;
          int Tk = T, ep = sl*T;
          float *hxp = hx, *hsp = hsave, *csp = csave; int *flp = flags;
          void* args[] = {(void*)&xF, (void*)&xB, (void*)&wF, (void*)&wB,
                          (void*)&hop, (void*)&hBs, (void*)&tOF, (void*)&tOB,
                          (void*)&Tk, (void*)&ep,
                          (void*)&hxp, (void*)&flp, (void*)&hsp, (void*)&csp};
          hipLaunchCooperativeKernel((const void*)k_lstm2s, dim3(C*4), dim3(512), args, 0, stream);
        }
        if (layer == 1){
          hipLaunchKernelGGL(k_feats_half, dim3(C*T/4), dim3(256), 0, stream,
                             h1s, fcw, fcb, feats, b0, logT, Tm1, sF*T, 0);
          hipLaunchKernelGGL(k_feats_half, dim3(C*T/4), dim3(256), 0, stream,
                             h1s, fcw, fcb, feats, b0, logT, Tm1, sB*T, 1);
        }
      }
    }
  }
  hipLaunchKernelGGL(k_viterbi, dim3(16), dim3(256), 0, stream, feats, trans, (float*)d_out);
}